// Round 1
// 88.072 us; speedup vs baseline: 1.0443x; 1.0443x over previous
//
#include <hip/hip_runtime.h>

// BinNormTrain: per-row solve sum_d sigmoid(x[d] + nu) == K (K=64) over rows of
// x:[16384,256] f32, then output sigmoid(x + nu).
// R1: 16 lanes/row, 30 bisections -> 97 us PASS (latency-bound, 4 waves/SIMD).
// R2: 64 lanes/row + bracketed Newton FAIL: strict bounds test mis-handled a
//     converged step (cand == nu == lo) -> catapulted to one-sided midpoint.
// R3: inclusive bounds test, 12 iters -> 92.8 us PASS.
// R4 (this): rocprof shows top-5 dispatches are all 256-MiB harness poison
//     fills (~45.6 us each, 74% HBM peak); kernel itself is < 44.7 us.
//     Remaining kernel lever: factor exp out of the iteration.
//       sigmoid(x_i + nu) = 1 / (1 + e_i * t),  e_i = exp(-x_i) precomputed,
//       t = exp(-nu) once per iteration (wave-uniform).
//     Removes 4 per-lane v_exp (8 cyc each, quarter-rate) from every Newton
//     iteration and from the epilogue; shortens nu->f dependency chain.
//     Range: e_i in [exp(-5.2), exp(5.2)], t in [exp(-12.2), exp(12.2)]
//     -> q in [2.7e-8, 3.6e7], safe in f32. 12 -> 10 iters (Newton converged
//     by ~6; inclusive-bounds keeps converged point fixed).

#define D_COLS 256
#define KF 64.0f
#define DELTA_F 7.0f
#define N_ITERS_NEWTON 10
#define LOG2E 1.44269504f

__global__ __launch_bounds__(256) void binnorm_kernel(const float* __restrict__ x,
                                                      float* __restrict__ out) {
    const int lane = threadIdx.x & 63;         // 64 lanes per row
    const int waveInBlock = threadIdx.x >> 6;  // 4 rows per block
    const int row = (blockIdx.x << 2) + waveInBlock;

    const float4* xr = reinterpret_cast<const float4*>(x + (size_t)row * D_COLS);
    float4 v = xr[lane];                       // 64 lanes x 16B = whole row, coalesced
    float xv[4] = {v.x, v.y, v.z, v.w};

    // Hoisted exponentials: e_i = exp(-x_i) = 2^(-x_i*log2e). Reused every
    // Newton iteration and in the epilogue -> only transcendental left in the
    // loop is one rcp per element plus one wave-uniform exp2 for t.
    float ev[4];
#pragma unroll
    for (int e = 0; e < 4; ++e)
        ev[e] = __builtin_amdgcn_exp2f(-LOG2E * xv[e]);

    // One-time reductions: sum (initial guess), max/min (bracket).
    float sum = (xv[0] + xv[1]) + (xv[2] + xv[3]);
    float mx = fmaxf(fmaxf(xv[0], xv[1]), fmaxf(xv[2], xv[3]));
    float mn = fminf(fminf(xv[0], xv[1]), fminf(xv[2], xv[3]));
#pragma unroll
    for (int m = 1; m <= 32; m <<= 1) {
        sum += __shfl_xor(sum, m);
        mx = fmaxf(mx, __shfl_xor(mx, m));
        mn = fminf(mn, __shfl_xor(mn, m));
    }

    float lo = -mx - DELTA_F;                  // f(lo) <= 256*sigmoid(-7) - 64 < 0
    float hi = -mn + DELTA_F;                  // f(hi) >= 256*sigmoid(+7) - 64 > 0

    // Mean-field initial guess: sigmoid(mean + nu)*256 = 64 -> nu = ln(1/3) - mean.
    float nu = -1.09861229f - sum * (1.0f / 256.0f);
    nu = fminf(fmaxf(nu, lo + 1e-3f), hi - 1e-3f);

    for (int it = 0; it < N_ITERS_NEWTON; ++it) {
        // t = exp(-nu); wave-uniform value (nu identical across lanes).
        float t = __builtin_amdgcn_exp2f(-LOG2E * nu);
        float f = 0.0f, fp = 0.0f;
#pragma unroll
        for (int e = 0; e < 4; ++e) {
            float s = __builtin_amdgcn_rcpf(1.0f + ev[e] * t);  // sigmoid(x_e+nu)
            f += s;
            fp += fmaf(-s, s, s);              // sigma*(1-sigma)
        }
#pragma unroll
        for (int m = 1; m <= 32; m <<= 1) {
            f += __shfl_xor(f, m);
            fp += __shfl_xor(fp, m);
        }
        f -= KF;
        // Bracket update by sign (wave-uniform -> cndmask).
        if (f < 0.0f) lo = nu; else hi = nu;
        // Newton step; INCLUSIVE bounds so a converged (zero-length) step
        // stays put instead of being kicked to the midpoint. NaN/inf from
        // degenerate fp fail the test and fall back to bisection.
        float cand = nu - f * __builtin_amdgcn_rcpf(fp);
        if (!(cand >= lo && cand <= hi)) cand = 0.5f * (lo + hi);
        nu = cand;
    }

    // Epilogue reuses e_i: no exp needed, just 4 rcp.
    float t = __builtin_amdgcn_exp2f(-LOG2E * nu);
    float4 o;
    o.x = __builtin_amdgcn_rcpf(1.0f + ev[0] * t);
    o.y = __builtin_amdgcn_rcpf(1.0f + ev[1] * t);
    o.z = __builtin_amdgcn_rcpf(1.0f + ev[2] * t);
    o.w = __builtin_amdgcn_rcpf(1.0f + ev[3] * t);
    reinterpret_cast<float4*>(out + (size_t)row * D_COLS)[lane] = o;
}

extern "C" void kernel_launch(void* const* d_in, const int* in_sizes, int n_in,
                              void* d_out, int out_size, void* d_ws, size_t ws_size,
                              hipStream_t stream) {
    const float* x = (const float*)d_in[0];
    float* out = (float*)d_out;
    const int rows = 16384;
    binnorm_kernel<<<dim3(rows / 4), dim3(256), 0, stream>>>(x, out);
}

// Round 2
// 73.559 us; speedup vs baseline: 1.2503x; 1.1973x over previous
//
#include <hip/hip_runtime.h>

// BinNormTrain: per-row solve sum_d sigmoid(x[d] + nu) == K (K=64) over rows of
// x:[16384,256] f32, then output sigmoid(x + nu).
// R1: 16 lanes/row, 30 bisections -> 97 us PASS.
// R3: 64 lanes/row, bracketed Newton, inclusive bounds, 12 iters -> 92.8 us.
// R4: hoist exp out of loop (sigmoid(x+nu) = 1/(1+e_i*t), t=exp(-nu)),
//     10 iters -> 88.1 us. Top-5 dispatches all harness poison fills (~44 us,
//     75% HBM peak); kernel ~10-15 us inferred from the R4 delta.
// R5 (this): kernel is issue-bound (16 waves serialized per SIMD). Per-iter
//     issue was ~142 cyc/row: only ~60 cyc is the 256 sigmoids; the 6-level
//     x2 shuffle reduce (~48) + wave-uniform tail (~30) served ONE row.
//     -> 4 rows per wave (16 lanes/row, 16 elems/lane): reduce is 4 levels
//        and serves 4 rows; Newton tail serves 4 rows (one per lane group).
//     -> Newton in t-domain: g(t)=sum 1/(1+e_i t), t'=t+f*t/fp. No exp2 in
//        the loop at all. g convex decreasing in t => every Newton step lands
//        in (t, t*] (tangent line below graph), so the bisection fallback is
//        only a NaN/degenerate-fp safety net.
//     -> 8 iters (quadratic; 10 and 12 gave identical absmax).
//     Per-row per-iter ~75 cyc; est kernel ~11 -> ~5 us.

#define D_COLS 256
#define KF 64.0f
#define DELTA_F 7.0f
#define N_ITERS 8
#define LOG2E 1.44269504f

__global__ __launch_bounds__(256) void binnorm_kernel(const float* __restrict__ x,
                                                      float* __restrict__ out) {
    const int lane = threadIdx.x & 63;
    const int waveInBlock = threadIdx.x >> 6;
    const int j = lane & 15;                  // lane within row (16 lanes/row)
    const int rowLocal = lane >> 4;           // row within wave (0..3)
    const int row = (blockIdx.x << 4) + (waveInBlock << 2) + rowLocal;

    // Lane j owns float4 chunks {j, j+16, j+32, j+48} of its row: each load
    // instruction reads a dense 256B segment per row-group (coalesced).
    const float4* xr = reinterpret_cast<const float4*>(x + (size_t)row * D_COLS);
    float4 c[4];
#pragma unroll
    for (int i = 0; i < 4; ++i) c[i] = xr[(i << 4) + j];

    // e_i = exp(-x_i) hoisted once; fused with sum/max/min scan.
    float ev[16];
    float sum = 0.0f, mx = -1e30f, mn = 1e30f;
#pragma unroll
    for (int i = 0; i < 4; ++i) {
        const float q[4] = {c[i].x, c[i].y, c[i].z, c[i].w};
#pragma unroll
        for (int e = 0; e < 4; ++e) {
            const float xv = q[e];
            sum += xv;
            mx = fmaxf(mx, xv);
            mn = fminf(mn, xv);
            ev[(i << 2) + e] = __builtin_amdgcn_exp2f(-LOG2E * xv);
        }
    }
    // 4-level reduce within each 16-lane row group (masks < 16 stay in-group).
#pragma unroll
    for (int m = 1; m <= 8; m <<= 1) {
        sum += __shfl_xor(sum, m);
        mx = fmaxf(mx, __shfl_xor(mx, m));
        mn = fminf(mn, __shfl_xor(mn, m));
    }

    const float lo = -mx - DELTA_F;           // f(lo) < 0 guaranteed
    const float hi = -mn + DELTA_F;           // f(hi) > 0 guaranteed
    // Mean-field guess: sigmoid(mean + nu)*256 = 64 -> nu = ln(1/3) - mean.
    float nu = -1.09861229f - sum * (1.0f / 256.0f);
    nu = fminf(fmaxf(nu, lo + 1e-3f), hi - 1e-3f);

    // t-domain bracket: t = exp(-nu) is decreasing in nu.
    // Range check: t in [exp(-11.5), exp(11.5)], q = ev*t <= ~3e6 -> f32 safe.
    float tlo = __builtin_amdgcn_exp2f(-LOG2E * hi);
    float thi = __builtin_amdgcn_exp2f(-LOG2E * lo);
    float t   = __builtin_amdgcn_exp2f(-LOG2E * nu);

    for (int it = 0; it < N_ITERS; ++it) {
        float f = 0.0f, fp = 0.0f;
#pragma unroll
        for (int e = 0; e < 16; ++e) {
            const float s = __builtin_amdgcn_rcpf(fmaf(ev[e], t, 1.0f));
            f += s;
            fp += fmaf(-s, s, s);             // sigma*(1-sigma) = s^2*ev*t
        }
#pragma unroll
        for (int m = 1; m <= 8; m <<= 1) {
            f += __shfl_xor(f, m);
            fp += __shfl_xor(fp, m);
        }
        f -= KF;
        // g decreasing in t: f>0 means t < t*.
        if (f > 0.0f) tlo = t; else thi = t;
        // Newton in t: t' = t + f*t/fp. Convexity => t' <= t*; from the left
        // t' > t, so steps are in-bracket. INCLUSIVE test keeps a converged
        // point fixed; NaN/inf (fp ~ 0) falls back to bisection.
        float cand = fmaf(f * t, __builtin_amdgcn_rcpf(fp), t);
        if (!(cand >= tlo && cand <= thi)) cand = 0.5f * (tlo + thi);
        t = cand;
    }

    // Epilogue: out = 1/(1 + e_i*t); mirrored coalesced stores.
    float4* orow = reinterpret_cast<float4*>(out + (size_t)row * D_COLS);
#pragma unroll
    for (int i = 0; i < 4; ++i) {
        float4 o;
        o.x = __builtin_amdgcn_rcpf(fmaf(ev[(i << 2) + 0], t, 1.0f));
        o.y = __builtin_amdgcn_rcpf(fmaf(ev[(i << 2) + 1], t, 1.0f));
        o.z = __builtin_amdgcn_rcpf(fmaf(ev[(i << 2) + 2], t, 1.0f));
        o.w = __builtin_amdgcn_rcpf(fmaf(ev[(i << 2) + 3], t, 1.0f));
        orow[(i << 4) + j] = o;
    }
}

extern "C" void kernel_launch(void* const* d_in, const int* in_sizes, int n_in,
                              void* d_out, int out_size, void* d_ws, size_t ws_size,
                              hipStream_t stream) {
    const float* x = (const float*)d_in[0];
    float* out = (float*)d_out;
    const int rows = 16384;
    binnorm_kernel<<<dim3(rows / 16), dim3(256), 0, stream>>>(x, out);
}

// Round 3
// 69.208 us; speedup vs baseline: 1.3289x; 1.0629x over previous
//
#include <hip/hip_runtime.h>

// BinNormTrain: per-row solve sum_d sigmoid(x[d] + nu) == K (K=64) over rows of
// x:[16384,256] f32, then output sigmoid(x + nu).
// R1: 16 lanes/row, 30 bisections -> 97 us.
// R3: 64 lanes/row, bracketed Newton, 12 iters -> 92.8 us.
// R4: hoist exp (sigmoid = 1/(1+e_i*t), t=exp(-nu)), 10 iters -> 88.1 us.
// R5: 4 rows/wave (16 lanes/row), t-domain Newton (no exp2 in loop), 8 iters
//     -> 73.6 us. Delta was 3x the issue model => kernel not issue-bound;
//     suspect DS-routed __shfl_xor chains (4-deep dependent, lgkmcnt waits,
//     only 4 waves/SIMD to hide them).
// R6 (this): replace ALL shuffle reductions with DPP butterflies -- 16-lane
//     reduce via quad_perm(1,0,3,2)=0xB1, quad_perm(2,3,0,1)=0x4E,
//     ROW_HALF_MIRROR=0x141, ROW_MIRROR=0x140. Each level = one full-rate
//     VALU op with DPP operand; zero DS traffic, zero lgkmcnt.
//     + early exit when __all(|f| < 1e-3) (f group-uniform; nu err <= 2e-4
//       -> out err <= 5e-5, far under the 0.0039 absmax floor).
//     + 4-way split accumulators (serial fma chain 16 -> 4 deep).

#define D_COLS 256
#define KF 64.0f
#define DELTA_F 7.0f
#define N_ITERS 8
#define LOG2E 1.44269504f

// DPP-permuted copy of v (row_mask=0xF, bank_mask=0xF, bound_ctrl=1).
template <int CTRL>
__device__ __forceinline__ float dpp_mov(float v) {
    return __int_as_float(__builtin_amdgcn_update_dpp(
        0, __float_as_int(v), CTRL, 0xF, 0xF, true));
}

// Butterfly sum over each 16-lane group, pure VALU.
__device__ __forceinline__ float dpp_sum16(float v) {
    v += dpp_mov<0xB1>(v);   // xor1  (quad_perm 1,0,3,2)
    v += dpp_mov<0x4E>(v);   // xor2  (quad_perm 2,3,0,1)
    v += dpp_mov<0x141>(v);  // pair across 4-boundary (ROW_HALF_MIRROR)
    v += dpp_mov<0x140>(v);  // pair across 8-boundary (ROW_MIRROR)
    return v;
}
__device__ __forceinline__ float dpp_max16(float v) {
    v = fmaxf(v, dpp_mov<0xB1>(v));
    v = fmaxf(v, dpp_mov<0x4E>(v));
    v = fmaxf(v, dpp_mov<0x141>(v));
    v = fmaxf(v, dpp_mov<0x140>(v));
    return v;
}
__device__ __forceinline__ float dpp_min16(float v) {
    v = fminf(v, dpp_mov<0xB1>(v));
    v = fminf(v, dpp_mov<0x4E>(v));
    v = fminf(v, dpp_mov<0x141>(v));
    v = fminf(v, dpp_mov<0x140>(v));
    return v;
}

__global__ __launch_bounds__(256) void binnorm_kernel(const float* __restrict__ x,
                                                      float* __restrict__ out) {
    const int lane = threadIdx.x & 63;
    const int waveInBlock = threadIdx.x >> 6;
    const int j = lane & 15;                  // lane within row (16 lanes/row)
    const int rowLocal = lane >> 4;           // row within wave (0..3)
    const int row = (blockIdx.x << 4) + (waveInBlock << 2) + rowLocal;

    // Lane j owns float4 chunks {j, j+16, j+32, j+48}: each load instruction
    // covers 4 dense 256B segments (one per row group) -- coalesced.
    const float4* xr = reinterpret_cast<const float4*>(x + (size_t)row * D_COLS);
    float4 c[4];
#pragma unroll
    for (int i = 0; i < 4; ++i) c[i] = xr[(i << 4) + j];

    // e_i = exp(-x_i) hoisted once; fused with sum/max/min scan.
    float ev[16];
    float sum = 0.0f, mx = -1e30f, mn = 1e30f;
#pragma unroll
    for (int i = 0; i < 4; ++i) {
        const float q[4] = {c[i].x, c[i].y, c[i].z, c[i].w};
#pragma unroll
        for (int e = 0; e < 4; ++e) {
            const float xv = q[e];
            sum += xv;
            mx = fmaxf(mx, xv);
            mn = fminf(mn, xv);
            ev[(i << 2) + e] = __builtin_amdgcn_exp2f(-LOG2E * xv);
        }
    }
    sum = dpp_sum16(sum);
    mx = dpp_max16(mx);
    mn = dpp_min16(mn);

    const float lo = -mx - DELTA_F;           // f(lo) < 0 guaranteed
    const float hi = -mn + DELTA_F;           // f(hi) > 0 guaranteed
    // Mean-field guess: sigmoid(mean + nu)*256 = 64 -> nu = ln(1/3) - mean.
    float nu = -1.09861229f - sum * (1.0f / 256.0f);
    nu = fminf(fmaxf(nu, lo + 1e-3f), hi - 1e-3f);

    // t-domain bracket: t = exp(-nu), decreasing in nu. g(t)=sum 1/(1+e_i t)
    // is convex decreasing => Newton from the left is monotone in-bracket;
    // the bisection fallback is a NaN/degenerate-fp safety net only.
    float tlo = __builtin_amdgcn_exp2f(-LOG2E * hi);
    float thi = __builtin_amdgcn_exp2f(-LOG2E * lo);
    float t   = __builtin_amdgcn_exp2f(-LOG2E * nu);

    for (int it = 0; it < N_ITERS; ++it) {
        // 4-way split accumulators: serial fma chain 16 -> 4 deep.
        float f0 = 0.f, f1 = 0.f, f2 = 0.f, f3 = 0.f;
        float p0 = 0.f, p1 = 0.f, p2 = 0.f, p3 = 0.f;
#pragma unroll
        for (int e = 0; e < 4; ++e) {
            float sa = __builtin_amdgcn_rcpf(fmaf(ev[4 * e + 0], t, 1.0f));
            float sb = __builtin_amdgcn_rcpf(fmaf(ev[4 * e + 1], t, 1.0f));
            float sc = __builtin_amdgcn_rcpf(fmaf(ev[4 * e + 2], t, 1.0f));
            float sd = __builtin_amdgcn_rcpf(fmaf(ev[4 * e + 3], t, 1.0f));
            f0 += sa; f1 += sb; f2 += sc; f3 += sd;
            p0 = fmaf(-sa, sa, p0 + sa);
            p1 = fmaf(-sb, sb, p1 + sb);
            p2 = fmaf(-sc, sc, p2 + sc);
            p3 = fmaf(-sd, sd, p3 + sd);
        }
        float f = dpp_sum16((f0 + f1) + (f2 + f3)) - KF;
        float fp = dpp_sum16((p0 + p1) + (p2 + p3));

        // Early exit: f is uniform within each 16-lane group, so __all over
        // the wave covers all 4 rows. |f|<1e-3 -> nu err <= 2e-4.
        if (__all(fabsf(f) < 1e-3f)) break;

        // g decreasing in t: f>0 means t < t*.
        if (f > 0.0f) tlo = t; else thi = t;
        // Newton in t; INCLUSIVE bounds test keeps a converged point fixed,
        // NaN/inf (fp ~ 0) falls back to bisection.
        float cand = fmaf(f * t, __builtin_amdgcn_rcpf(fp), t);
        if (!(cand >= tlo && cand <= thi)) cand = 0.5f * (tlo + thi);
        t = cand;
    }

    // Epilogue: out = 1/(1 + e_i*t); mirrored coalesced stores.
    float4* orow = reinterpret_cast<float4*>(out + (size_t)row * D_COLS);
#pragma unroll
    for (int i = 0; i < 4; ++i) {
        float4 o;
        o.x = __builtin_amdgcn_rcpf(fmaf(ev[(i << 2) + 0], t, 1.0f));
        o.y = __builtin_amdgcn_rcpf(fmaf(ev[(i << 2) + 1], t, 1.0f));
        o.z = __builtin_amdgcn_rcpf(fmaf(ev[(i << 2) + 2], t, 1.0f));
        o.w = __builtin_amdgcn_rcpf(fmaf(ev[(i << 2) + 3], t, 1.0f));
        orow[(i << 4) + j] = o;
    }
}

extern "C" void kernel_launch(void* const* d_in, const int* in_sizes, int n_in,
                              void* d_out, int out_size, void* d_ws, size_t ws_size,
                              hipStream_t stream) {
    const float* x = (const float*)d_in[0];
    float* out = (float*)d_out;
    const int rows = 16384;
    binnorm_kernel<<<dim3(rows / 16), dim3(256), 0, stream>>>(x, out);
}